// Round 4
// baseline (59.318 us; speedup 1.0000x reference)
//
#include <hip/hip_runtime.h>

#define NN 1024
#define DD 256
#define HH 256

typedef __attribute__((ext_vector_type(8))) short short8;
typedef __attribute__((ext_vector_type(4))) float floatx4;

// ---- ws layout (bytes) ----
// Permuted h' space: 288 slots = [positives (P) | zero-pad to P32 | negatives | zero-pad]
#define ZB_OFF   0u           // bf16 zb[1024][256]                      512 KiB
#define WC_OFF   524288u      // bf16 Wcat[592][256]: rows 0..287 R-half (|w2|-scaled, perm),
                              //   288..575 C-half (-|w2|-scaled, perm), 576 wc, 577..591 zero
#define B1F_OFF  827392u      // f32 b1f[592]
#define PV_OFF   829760u      // int P (count of w2>0)
#define RF_OFF   1048576u     // f32 Rf[1024][288]   (perm+pad)          1.125 MiB
#define CT_OFF   2228224u     // float4 Ct4[72][1024]: Ct4[g][j] = 4 h' (4g..4g+3) of column j
#define KV_OFF   3407872u     // f32 Kv[1024]  (= z@wc + b2)

__device__ __forceinline__ unsigned short f2bf(float x) {  // RNE f32->bf16
  unsigned u = __float_as_uint(x);
  return (unsigned short)((u + 0x7FFFu + ((u >> 16) & 1u)) >> 16);
}

// ---------------- k0: prep ----------------
__global__ __launch_bounds__(256) void k0_prep(const float* __restrict__ z,
    const float* __restrict__ W1, const float* __restrict__ b1,
    const float* __restrict__ W2, const float* __restrict__ b2,
    char* __restrict__ ws) {
  const int b = blockIdx.x, t = threadIdx.x;
  unsigned short* zb = (unsigned short*)(ws + ZB_OFF);
  unsigned short* Wc = (unsigned short*)(ws + WC_OFF);
  float* b1f = (float*)(ws + B1F_OFF);

  if (b < 256) {                       // z -> bf16, 1 float4 per thread
    const int g = b * 256 + t;
    float4 v = ((const float4*)z)[g];
    ushort4 u;
    u.x = f2bf(v.x); u.y = f2bf(v.y); u.z = f2bf(v.z); u.w = f2bf(v.w);
    ((ushort4*)zb)[g] = u;
    return;
  }
  if (b < 400) {                       // Wcat rows q = 4*(b-256)+(t>>6) in [0,576)
    __shared__ unsigned long long masks[4];
    __shared__ short inv[288];
    const bool pos = W2[t] > 0.f;
    unsigned long long m = __ballot(pos);
    if ((t & 63) == 0) masks[t >> 6] = m;
    inv[t] = -1;
    if (t < 32) inv[256 + t] = -1;
    __syncthreads();
    int P = 0;
    #pragma unroll
    for (int w = 0; w < 4; ++w) P += __popcll(masks[w]);
    const int w = t >> 6;
    int below = __popcll(masks[w] & ((1ull << (t & 63)) - 1ull));
    #pragma unroll
    for (int wi = 0; wi < 4; ++wi) if (wi < w) below += __popcll(masks[wi]);
    const int P32 = (P + 31) & ~31;
    const int dest = pos ? below : (P32 + (t - below));
    inv[dest] = (short)t;
    __syncthreads();

    const int q = (b - 256) * 4 + (t >> 6);     // 0..575
    const int d0 = (t & 63) * 4;
    const bool topR = q < 288;
    const int hidx = topR ? q : q - 288;
    const short oh = inv[hidx];
    ushort4 u = {0, 0, 0, 0};
    float bias = 0.f;
    if (oh >= 0) {
      const float wa = fabsf(W2[oh]);
      const float sc = topR ? wa : -wa;          // C-half carries the negation (Cn = -C~)
      const float4 v = *(const float4*)(W1 + oh * 512 + (topR ? 0 : 256) + d0);
      u.x = f2bf(v.x * sc); u.y = f2bf(v.y * sc);
      u.z = f2bf(v.z * sc); u.w = f2bf(v.w * sc);
      bias = topR ? b1[oh] * wa : 0.f;
    }
    ((ushort4*)(Wc + q * 256))[d0 >> 2] = u;
    if (d0 == 0) b1f[q] = bias;
    if (b == 256 && t == 0) *(int*)(ws + PV_OFF) = P;
    return;
  }
  // b in [400,404): wc quarter: wc[d] = sum_h W2[h]*W1[h][256+d] -> Wcat row 576
  {
    __shared__ float part[4][64];
    const int w = t >> 6, dl = t & 63;
    const int d = (b - 400) * 64 + dl;
    float acc = 0.f;
    const float* col = W1 + 256 + d;
    #pragma unroll 8
    for (int h = w * 64; h < w * 64 + 64; ++h) acc += W2[h] * col[h * 512];
    part[w][dl] = acc;
    __syncthreads();
    if (w == 0) {
      float s = part[0][dl] + part[1][dl] + part[2][dl] + part[3][dl];
      Wc[576 * 256 + d] = f2bf(s);
    }
    if (b == 400) {
      for (int r = 577; r < 592; ++r) Wc[r * 256 + t] = 0;   // zero pad rows
      if (t == 0) b1f[576] = b2[0];
      if (t < 15) b1f[577 + t] = 0.f;
    }
  }
}

// ---------------- k1: fc1 GEMM via bf16 MFMA -> f32 outputs ----------------
// G[i][q] = zb[i][:] . Wcat[q][:] + b1f[q]
//   q<288      -> Rf[i][q]           (row-major f32)
//   q in [288,576) -> Ct4 transposed-packed f32
//   q-tile 36  -> Kv (col 0)
__global__ __launch_bounds__(64) void k1_mfma(char* __restrict__ ws) {
  __shared__ float tile[16][17];
  const unsigned short* zb = (const unsigned short*)(ws + ZB_OFF);
  const unsigned short* Wcu = (const unsigned short*)(ws + WC_OFF);
  const float* b1f = (const float*)(ws + B1F_OFF);
  float* Rf = (float*)(ws + RF_OFF);
  float4* Ct4 = (float4*)(ws + CT_OFF);
  float* Kv = (float*)(ws + KV_OFF);

  const int l = threadIdx.x;
  const int i0 = blockIdx.x * 16, q0 = blockIdx.y * 16;
  const short* A = (const short*)zb + (i0 + (l & 15)) * 256 + ((l >> 4) * 8);
  const short* B = (const short*)Wcu + (q0 + (l & 15)) * 256 + ((l >> 4) * 8);
  floatx4 acc = {0.f, 0.f, 0.f, 0.f};
  #pragma unroll
  for (int kk = 0; kk < 8; ++kk) {
    short8 a  = *(const short8*)(A + kk * 32);
    short8 bb = *(const short8*)(B + kk * 32);
    acc = __builtin_amdgcn_mfma_f32_16x16x32_bf16(a, bb, acc, 0, 0, 0);
  }
  const int col = l & 15, r0 = (l >> 4) * 4;   // D: col=lane&15, row=(lane>>4)*4+reg
  if (q0 < 288) {
    const float bias = b1f[q0 + col];
    #pragma unroll
    for (int q = 0; q < 4; ++q)
      Rf[(i0 + r0 + q) * 288 + q0 + col] = acc[q] + bias;
  } else if (q0 < 576) {
    #pragma unroll
    for (int q = 0; q < 4; ++q) tile[r0 + q][col] = acc[q];   // tile[j_local][h_local]
    __syncthreads();
    const int jl = l & 15, qg = l >> 4;         // qg: which 4-h group
    float4 v;
    v.x = tile[jl][qg * 4 + 0]; v.y = tile[jl][qg * 4 + 1];
    v.z = tile[jl][qg * 4 + 2]; v.w = tile[jl][qg * 4 + 3];
    const int q0c = q0 - 288;
    Ct4[((q0c >> 2) + qg) * 1024 + (i0 + jl)] = v;
  } else if (col == 0) {
    const float bias = b1f[576];                // = b2
    #pragma unroll
    for (int q = 0; q < 4; ++q) Kv[i0 + r0 + q] = acc[q] + bias;
  }
}

// ---------------- k2: pairwise decode, plain-f32 VALU ----------------
// out[i,j] = sigmoid( sum_ch s_ch * sum_{h in ch} max(Rf[i,h'], Ct[h',j]) + Kv[j] )
// 9 sign-pure chunks of 32 h'. C in VGPRs (double-buffered), R via uniform scalar loads.
__global__ __launch_bounds__(64) void k2_pair(const float* __restrict__ Rf,
    const float4* __restrict__ Ct4, const float* __restrict__ Kv,
    const int* __restrict__ Pp, float* __restrict__ out) {
  const int lane = threadIdx.x;
  const int i0 = blockIdx.x * 8;
  const int j  = blockIdx.y * 64 + lane;
  const int P = Pp[0];

  float acc[8] = {};
  float4 cbA[8], cbB[8];

#define LOADC(BUF, CH) do { \
    _Pragma("unroll") \
    for (int g = 0; g < 8; ++g) BUF[g] = Ct4[((CH) * 8 + g) * 1024 + j]; \
  } while (0)

#define COMPC(BUF, CH) do { \
    const float sch = ((CH) * 32 < P) ? 1.f : -1.f; \
    _Pragma("unroll") \
    for (int i = 0; i < 8; ++i) { \
      const float* rrow = Rf + (i0 + i) * 288 + (CH) * 32; \
      float p0 = 0.f, p1 = 0.f; \
      _Pragma("unroll") \
      for (int g = 0; g < 8; ++g) { \
        const float4 c = BUF[g]; \
        p0 += fmaxf(rrow[4 * g + 0], c.x); \
        p1 += fmaxf(rrow[4 * g + 1], c.y); \
        p0 += fmaxf(rrow[4 * g + 2], c.z); \
        p1 += fmaxf(rrow[4 * g + 3], c.w); \
      } \
      acc[i] = fmaf(sch, p0 + p1, acc[i]); \
    } \
  } while (0)

  LOADC(cbA, 0);
  #pragma unroll 1
  for (int chp = 0; chp < 4; ++chp) {
    const int c0 = 2 * chp;
    LOADC(cbB, c0 + 1);
    COMPC(cbA, c0);
    LOADC(cbA, c0 + 2);          // chp=3 loads chunk 8 (valid; chunks are 0..8)
    COMPC(cbB, c0 + 1);
  }
  COMPC(cbA, 8);

  const float kv = Kv[j];
  #pragma unroll
  for (int i = 0; i < 8; ++i) {
    const float x = acc[i] + kv;
    out[(i0 + i) * NN + j] = 1.f / (1.f + __expf(-x));
  }
#undef LOADC
#undef COMPC
}

extern "C" void kernel_launch(void* const* d_in, const int* in_sizes, int n_in,
                              void* d_out, int out_size, void* d_ws, size_t ws_size,
                              hipStream_t stream) {
  const float* z  = (const float*)d_in[0];
  const float* W1 = (const float*)d_in[1];
  const float* b1 = (const float*)d_in[2];
  const float* W2 = (const float*)d_in[3];
  const float* b2 = (const float*)d_in[4];
  float* out = (float*)d_out;
  char* ws = (char*)d_ws;

  k0_prep<<<404, 256, 0, stream>>>(z, W1, b1, W2, b2, ws);
  k1_mfma<<<dim3(64, 37), 64, 0, stream>>>(ws);
  k2_pair<<<dim3(128, 16), 64, 0, stream>>>(
      (const float*)(ws + RF_OFF), (const float4*)(ws + CT_OFF),
      (const float*)(ws + KV_OFF), (const int*)(ws + PV_OFF), out);
}